// Round 2
// baseline (27156.097 us; speedup 1.0000x reference)
//
#include <hip/hip_runtime.h>
#include <hip/hip_bf16.h>

typedef __bf16 bf16_t;
typedef __bf16 bf16x8 __attribute__((ext_vector_type(8)));
typedef float f32x4 __attribute__((ext_vector_type(4)));

#define TLEN 128
#define BATCHN 512
#define OBS 256
#define HID 1024
#define STATEDIM 1024
#define ROWS (TLEN * BATCHN)   // 65536
#define RKDT 0.25f

enum { EPI_F32 = 0, EPI_GI, EPI_TANH, EPI_K1, EPI_K2, EPI_K3, EPI_K4 };

__device__ __forceinline__ void gload_lds16(const bf16_t* g, bf16_t* l) {
  __builtin_amdgcn_global_load_lds(
      (const __attribute__((address_space(1))) void*)g,
      (__attribute__((address_space(3))) void*)l, 16, 0, 0);
}

__device__ __forceinline__ bf16_t f2bf(float x) { return (bf16_t)x; }

// C = epi(A[M][K] @ Wt[N][K]^T + bias). A,Wt bf16 row-major, fp32 acc.
// m97 structure: 128x128 tile, BK=32, 4 waves (2x2), 16x16x32 MFMA,
// global_load_lds width=16, double-buffered LDS.
// K-epilogues: Z/ZN fp32 stride 1024; S2 split-bf16 [row][2048] (hi|lo).
template<int EPI>
__global__ __launch_bounds__(256)
void gemm_bt(const bf16_t* __restrict__ A, const bf16_t* __restrict__ Wt,
             const float* __restrict__ bias, int M, int N, int K,
             float* __restrict__ outF, bf16_t* __restrict__ outB,
             float* __restrict__ Z, float* __restrict__ ZN,
             bf16_t* __restrict__ S2)
{
  __shared__ __align__(16) bf16_t As[2][128 * 32];
  __shared__ __align__(16) bf16_t Bs[2][128 * 32];
  const int tid = threadIdx.x;
  const int lane = tid & 63;
  const int wave = tid >> 6;
  const int nbn = N >> 7;
  const int bm = blockIdx.x / nbn;
  const int bn = blockIdx.x % nbn;
  const int m0 = bm << 7, n0 = bn << 7;
  const int wr = wave >> 1, wc = wave & 1;
  const int srow = tid >> 2;          // staging row in tile (0..63)
  const int scol = (tid & 3) << 3;    // staging col (bf16 elems)

  f32x4 acc[4][4] = {};
  const int nk = K >> 5;
  int cur = 0;

  {
    const bf16_t* ga = A  + (size_t)(m0 + srow) * K + scol;
    const bf16_t* gb = Wt + (size_t)(n0 + srow) * K + scol;
    bf16_t* la = &As[0][tid * 8];
    bf16_t* lb = &Bs[0][tid * 8];
    gload_lds16(ga, la);
    gload_lds16(ga + (size_t)64 * K, la + 2048);
    gload_lds16(gb, lb);
    gload_lds16(gb + (size_t)64 * K, lb + 2048);
  }

  for (int ks = 0; ks < nk; ++ks) {
    __syncthreads();  // drains vmcnt(0): staged tile ready
    if (ks + 1 < nk) {
      const bf16_t* ga = A  + (size_t)(m0 + srow) * K + (ks + 1) * 32 + scol;
      const bf16_t* gb = Wt + (size_t)(n0 + srow) * K + (ks + 1) * 32 + scol;
      bf16_t* la = &As[cur ^ 1][tid * 8];
      bf16_t* lb = &Bs[cur ^ 1][tid * 8];
      gload_lds16(ga, la);
      gload_lds16(ga + (size_t)64 * K, la + 2048);
      gload_lds16(gb, lb);
      gload_lds16(gb + (size_t)64 * K, lb + 2048);
    }
    const int kb = (lane >> 4) << 3;
    const int rr = lane & 15;
    bf16x8 af[4], bfr[4];
#pragma unroll
    for (int i = 0; i < 4; ++i) {
      af[i]  = *(const bf16x8*)&As[cur][(wr * 64 + i * 16 + rr) * 32 + kb];
      bfr[i] = *(const bf16x8*)&Bs[cur][(wc * 64 + i * 16 + rr) * 32 + kb];
    }
#pragma unroll
    for (int i = 0; i < 4; ++i)
#pragma unroll
      for (int j = 0; j < 4; ++j)
        acc[i][j] = __builtin_amdgcn_mfma_f32_16x16x32_bf16(af[i], bfr[j], acc[i][j], 0, 0, 0);
    cur ^= 1;
  }

  // C/D layout: col=lane&15, row=(lane>>4)*4+reg  [m89-verified]
  const int cb = n0 + wc * 64 + (lane & 15);
  const int rb = m0 + wr * 64 + ((lane >> 4) << 2);
#pragma unroll
  for (int j = 0; j < 4; ++j) {
    const int c = cb + j * 16;
    float bv = 0.f;
    if constexpr (EPI != EPI_F32) bv = bias[c];
#pragma unroll
    for (int i = 0; i < 4; ++i) {
      const int r0 = rb + i * 16;
#pragma unroll
      for (int r = 0; r < 4; ++r) {
        const size_t idx = (size_t)(r0 + r) * N + c;
        const float v = acc[i][j][r];
        if constexpr (EPI == EPI_F32) {
          outF[idx] = v;
        } else if constexpr (EPI == EPI_GI) {
          outF[idx] = v + bv;
        } else if constexpr (EPI == EPI_TANH) {
          outB[idx] = f2bf(tanhf(v + bv));
        } else {
          const float k = v + bv;          // N==1024 here; idx = row*1024+c
          const size_t si = (size_t)(r0 + r) * 2048 + c;
          float s;
          if constexpr (EPI == EPI_K1) {
            const float z = Z[idx];
            ZN[idx] = z + (RKDT / 6.f) * k;
            s = z + 0.5f * RKDT * k;
          } else if constexpr (EPI == EPI_K2) {
            const float z = Z[idx];
            ZN[idx] += (RKDT / 3.f) * k;
            s = z + 0.5f * RKDT * k;
          } else if constexpr (EPI == EPI_K3) {
            const float z = Z[idx];
            ZN[idx] += (RKDT / 3.f) * k;
            s = z + RKDT * k;
          } else {  // K4
            s = ZN[idx] + (RKDT / 6.f) * k;
            Z[idx] = s;
          }
          const bf16_t hi = f2bf(s);
          S2[si] = hi;
          S2[si + 1024] = f2bf(s - (float)hi);
        }
      }
    }
  }
}

// per-row LayerNorm(+bias) + LeakyReLU(0.1), row width 1024.
// SPLIT=0: bf16 out stride 1024. SPLIT=1: split-bf16 out [row][2048] + f32 Zf.
template<bool SPLIT>
__global__ __launch_bounds__(256)
void ln_leaky(const float* __restrict__ pre, const float* __restrict__ b,
              const float* __restrict__ g, const float* __restrict__ bet,
              bf16_t* __restrict__ outB, float* __restrict__ zf)
{
  const int row = blockIdx.x;
  const int tid = threadIdx.x;
  const float* p = pre + (size_t)row * 1024;
  float v[4];
  float s = 0.f, s2 = 0.f;
#pragma unroll
  for (int i = 0; i < 4; ++i) {
    const int c = tid + i * 256;
    v[i] = p[c] + b[c];
    s += v[i]; s2 += v[i] * v[i];
  }
#pragma unroll
  for (int o = 32; o; o >>= 1) { s += __shfl_down(s, o); s2 += __shfl_down(s2, o); }
  __shared__ float rs[4], rs2[4];
  if ((tid & 63) == 0) { rs[tid >> 6] = s; rs2[tid >> 6] = s2; }
  __syncthreads();
  s = rs[0] + rs[1] + rs[2] + rs[3];
  s2 = rs2[0] + rs2[1] + rs2[2] + rs2[3];
  const float mu = s * (1.f / 1024.f);
  const float var = s2 * (1.f / 1024.f) - mu * mu;
  const float rstd = rsqrtf(var + 1e-5f);
#pragma unroll
  for (int i = 0; i < 4; ++i) {
    const int c = tid + i * 256;
    float h = (v[i] - mu) * rstd * g[c] + bet[c];
    h = h >= 0.f ? h : 0.1f * h;
    if constexpr (SPLIT) {
      const bf16_t hi = f2bf(h);
      outB[(size_t)row * 2048 + c] = hi;
      outB[(size_t)row * 2048 + 1024 + c] = f2bf(h - (float)hi);
      zf[(size_t)row * 1024 + c] = h;
    } else {
      outB[(size_t)row * 1024 + c] = f2bf(h);
    }
  }
}

// GRU gating. gi f32 (bih included); gh f32 raw h@Whh^T (bhh added here).
// Writes h (f32) and split-bf16 h for the next Whh GEMM.
__global__ __launch_bounds__(256)
void gru_gate(const float* __restrict__ gi_t, const float* __restrict__ gh,
              const float* __restrict__ bhh,
              float* __restrict__ h, bf16_t* __restrict__ hb)
{
  const int idx = blockIdx.x * 256 + threadIdx.x;  // 512*1024
  const int r = idx >> 10, j = idx & 1023;
  const size_t rb = (size_t)r * 3072;
  const float ir  = gi_t[rb + j];
  const float iz  = gi_t[rb + 1024 + j];
  const float inn = gi_t[rb + 2048 + j];
  const float hr = gh[rb + j]        + bhh[j];
  const float hz = gh[rb + 1024 + j] + bhh[1024 + j];
  const float hn = gh[rb + 2048 + j] + bhh[2048 + j];
  const float rg = 1.f / (1.f + expf(-(ir + hr)));
  const float zg = 1.f / (1.f + expf(-(iz + hz)));
  const float n  = tanhf(inn + rg * hn);
  const float ho = (1.f - zg) * n + zg * h[idx];
  h[idx] = ho;
  const bf16_t hi = f2bf(ho);
  hb[(size_t)r * 2048 + j] = hi;
  hb[(size_t)r * 2048 + 1024 + j] = f2bf(ho - (float)hi);
}

// in[R][C] fp32 -> out[C][R] bf16
__global__ __launch_bounds__(256)
void transpose_bf16(const float* __restrict__ in, bf16_t* __restrict__ out, int R, int C)
{
  __shared__ float t[32][33];
  const int c0 = blockIdx.x * 32, r0 = blockIdx.y * 32;
  const int tx = threadIdx.x & 31, ty = threadIdx.x >> 5;  // 32x8
#pragma unroll
  for (int i = 0; i < 32; i += 8)
    t[ty + i][tx] = in[(size_t)(r0 + ty + i) * C + c0 + tx];
  __syncthreads();
#pragma unroll
  for (int i = 0; i < 32; i += 8)
    out[(size_t)(c0 + ty + i) * R + r0 + tx] = f2bf(t[tx][ty + i]);
}

__global__ __launch_bounds__(256)
void f2b_kernel(const float* __restrict__ in, bf16_t* __restrict__ out, int n)
{
  const int i = blockIdx.x * 256 + threadIdx.x;
  if (i < n) out[i] = f2bf(in[i]);
}

// out[n][2K] = {in[n][K], in[n][K]}  (K-duplication for split-operand GEMMs)
__global__ __launch_bounds__(256)
void dup2_kernel(const bf16_t* __restrict__ in, bf16_t* __restrict__ out, int N, int K)
{
  const int idx = blockIdx.x * 256 + threadIdx.x;
  if (idx >= N * 2 * K) return;
  const int n = idx / (2 * K);
  const int kk = idx - n * 2 * K;
  const int k = kk < K ? kk : kk - K;
  out[idx] = in[(size_t)n * K + k];
}

__global__ __launch_bounds__(256)
void write_out_kernel(const float* __restrict__ h, float* __restrict__ out)
{
  const int idx = blockIdx.x * 256 + threadIdx.x;  // 512*1024
  const int r = idx >> 10, c = idx & 1023;
  const float v = h[idx];
  if (c < 512) out[(size_t)r * 512 + c] = v;
  else         out[262144 + (size_t)r * 512 + (c - 512)] = v;
}

__global__ void sentinel_kernel(float* out, float code) {
  if (threadIdx.x == 0 && blockIdx.x == 0) out[0] = code;
}

extern "C" void kernel_launch(void* const* d_in, const int* in_sizes, int n_in,
                              void* d_out, int out_size, void* d_ws, size_t ws_size,
                              hipStream_t stream)
{
  const float* xs    = (const float*)d_in[0];
  const float* obs_W = (const float*)d_in[1];
  const float* obs_b = (const float*)d_in[2];
  const float* obs_g = (const float*)d_in[3];
  const float* obs_be= (const float*)d_in[4];
  const float* lat_W = (const float*)d_in[5];
  const float* lat_b = (const float*)d_in[6];
  const float* lat_g = (const float*)d_in[7];
  const float* lat_be= (const float*)d_in[8];
  const float* W0    = (const float*)d_in[9];
  const float* b0    = (const float*)d_in[10];
  const float* W1    = (const float*)d_in[11];
  const float* b1    = (const float*)d_in[12];
  const float* W2    = (const float*)d_in[13];
  const float* b2    = (const float*)d_in[14];
  const float* Wih   = (const float*)d_in[15];
  const float* Whh   = (const float*)d_in[16];
  const float* bih   = (const float*)d_in[17];
  const float* bhh   = (const float*)d_in[18];

  char* ws = (char*)d_ws;
  size_t off = 0;
  auto alloc = [&](size_t bytes) { char* p = ws + off; off += bytes; return p; };

  // ---- static region (~60.5 MB) ----
  bf16_t* OBSWT = (bf16_t*)alloc((size_t)HID * OBS * 2);        // [1024][256]
  bf16_t* LATWT = (bf16_t*)alloc((size_t)STATEDIM * HID * 2);   // [1024][1024]
  bf16_t* W0T2  = (bf16_t*)alloc((size_t)HID * 2048 * 2);       // [1024][2048]
  bf16_t* W1T   = (bf16_t*)alloc((size_t)HID * HID * 2);
  bf16_t* W2T   = (bf16_t*)alloc((size_t)STATEDIM * HID * 2);
  bf16_t* WIH2  = (bf16_t*)alloc((size_t)3072 * 2048 * 2);
  bf16_t* WHH2  = (bf16_t*)alloc((size_t)3072 * 2048 * 2);
  float*  GHf   = (float*)alloc((size_t)512 * 3072 * 4);
  float*  Hf    = (float*)alloc((size_t)512 * 1024 * 4);
  bf16_t* HBF0  = (bf16_t*)alloc((size_t)512 * 2048 * 2);
  bf16_t* HBF1  = (bf16_t*)alloc((size_t)512 * 2048 * 2);
  bf16_t* W0T   = (bf16_t*)alloc((size_t)HID * HID * 2);        // temp
  bf16_t* WIHB  = (bf16_t*)alloc((size_t)3072 * 1024 * 2);      // temp
  bf16_t* WHHB  = (bf16_t*)alloc((size_t)3072 * 1024 * 2);      // temp
  const size_t staticEnd = off;

  // ---- choose chunk count: smallest nc whose arena fits ----
  // per-row arena: A1(4096) A2(4096) H1(2048) H2(2048) S2(4096) XSB(512) = 16896 B
  // GI f32 (12288 B/row) overlaps A1+A2+H1+H2 exactly.
  int nc = -1;
  const int ncs[8] = {1, 2, 4, 8, 16, 32, 64, 128};
  for (int i = 0; i < 8; ++i) {
    const size_t R = (size_t)ROWS / ncs[i];
    if (staticEnd + R * 16896 <= ws_size) { nc = ncs[i]; break; }
  }
  if (nc < 0) {  // encode ws MB so the next round can read it from absmax
    sentinel_kernel<<<1, 1, 0, stream>>>((float*)d_out,
                                         -(1000000.0f + (float)(ws_size >> 20)));
    return;
  }
  const int R = ROWS / nc;
  char* arena = ws + staticEnd;
  float*  A1f  = (float*)(arena);                       // pre-LN / ZN
  float*  A2f  = (float*)(arena + (size_t)R * 4096);    // z fp32
  bf16_t* H1b  = (bf16_t*)(arena + (size_t)R * 8192);
  bf16_t* H2b  = (bf16_t*)(arena + (size_t)R * 10240);
  bf16_t* S2b  = (bf16_t*)(arena + (size_t)R * 12288);  // split z / stage input
  bf16_t* XSBc = (bf16_t*)(arena + (size_t)R * 16384);
  float*  GIf  = (float*)(arena);                       // gi f32, overlaps A1..H2

  auto gemm = [&](int epi, const bf16_t* A, const bf16_t* Wt, const float* bias,
                  int M, int N, int K, float* oF, bf16_t* oB) {
    dim3 g((M / 128) * (N / 128)), b(256);
    switch (epi) {
      case EPI_F32:  gemm_bt<EPI_F32><<<g, b, 0, stream>>>(A, Wt, bias, M, N, K, oF, oB, A2f, A1f, S2b); break;
      case EPI_GI:   gemm_bt<EPI_GI><<<g, b, 0, stream>>>(A, Wt, bias, M, N, K, oF, oB, A2f, A1f, S2b); break;
      case EPI_TANH: gemm_bt<EPI_TANH><<<g, b, 0, stream>>>(A, Wt, bias, M, N, K, oF, oB, A2f, A1f, S2b); break;
      case EPI_K1:   gemm_bt<EPI_K1><<<g, b, 0, stream>>>(A, Wt, bias, M, N, K, oF, oB, A2f, A1f, S2b); break;
      case EPI_K2:   gemm_bt<EPI_K2><<<g, b, 0, stream>>>(A, Wt, bias, M, N, K, oF, oB, A2f, A1f, S2b); break;
      case EPI_K3:   gemm_bt<EPI_K3><<<g, b, 0, stream>>>(A, Wt, bias, M, N, K, oF, oB, A2f, A1f, S2b); break;
      case EPI_K4:   gemm_bt<EPI_K4><<<g, b, 0, stream>>>(A, Wt, bias, M, N, K, oF, oB, A2f, A1f, S2b); break;
    }
  };

  // ---- weight prep (every call; ~30 MB of traffic, negligible) ----
  transpose_bf16<<<dim3(HID / 32, OBS / 32), 256, 0, stream>>>(obs_W, OBSWT, OBS, HID);
  transpose_bf16<<<dim3(STATEDIM / 32, HID / 32), 256, 0, stream>>>(lat_W, LATWT, HID, STATEDIM);
  transpose_bf16<<<dim3(HID / 32, STATEDIM / 32), 256, 0, stream>>>(W0, W0T, STATEDIM, HID);
  dup2_kernel<<<(HID * 2048) / 256, 256, 0, stream>>>(W0T, W0T2, HID, 1024);
  transpose_bf16<<<dim3(HID / 32, HID / 32), 256, 0, stream>>>(W1, W1T, HID, HID);
  transpose_bf16<<<dim3(STATEDIM / 32, HID / 32), 256, 0, stream>>>(W2, W2T, HID, STATEDIM);
  f2b_kernel<<<(3072 * 1024) / 256, 256, 0, stream>>>(Wih, WIHB, 3072 * 1024);
  dup2_kernel<<<(3072 * 2048) / 256, 256, 0, stream>>>(WIHB, WIH2, 3072, 1024);
  f2b_kernel<<<(3072 * 1024) / 256, 256, 0, stream>>>(Whh, WHHB, 3072 * 1024);
  dup2_kernel<<<(3072 * 2048) / 256, 256, 0, stream>>>(WHHB, WHH2, 3072, 1024);

  hipMemsetAsync(Hf, 0, (size_t)512 * 1024 * 4, stream);
  hipMemsetAsync(HBF0, 0, (size_t)512 * 2048 * 2, stream);
  bf16_t* HBF[2] = { HBF0, HBF1 };
  int cur = 0;
  const int TS = R / BATCHN;  // timesteps per chunk

  for (int c = 0; c < nc; ++c) {
    // encoder MLPs for this chunk of rows
    f2b_kernel<<<R, 256, 0, stream>>>(xs + (size_t)c * R * OBS, XSBc, R * OBS);
    gemm(EPI_F32, XSBc, OBSWT, nullptr, R, HID, OBS, A1f, nullptr);
    ln_leaky<false><<<R, 256, 0, stream>>>(A1f, obs_b, obs_g, obs_be, H1b, nullptr);
    gemm(EPI_F32, H1b, LATWT, nullptr, R, STATEDIM, HID, A1f, nullptr);
    ln_leaky<true><<<R, 256, 0, stream>>>(A1f, lat_b, lat_g, lat_be, S2b, A2f);

    // RK4: 4 steps x 4 stages x 3 GEMMs, all R rows in parallel
    for (int step = 0; step < 4; ++step) {
      for (int stg = 0; stg < 4; ++stg) {
        gemm(EPI_TANH, S2b, W0T2, b0, R, HID, 2048, nullptr, H1b);
        gemm(EPI_TANH, H1b, W1T, b1, R, HID, HID, nullptr, H2b);
        gemm(EPI_K1 + stg, H2b, W2T, b2, R, STATEDIM, HID, nullptr, nullptr);
      }
    }

    // gi = z_final @ Wih^T + bih (split-z, fp32 out) — overwrites dead A1..H2
    gemm(EPI_GI, S2b, WIH2, bih, R, 3072, 2048, GIf, nullptr);

    // sequential GRU over this chunk's timesteps
    for (int lt = 0; lt < TS; ++lt) {
      gemm(EPI_F32, HBF[cur], WHH2, nullptr, BATCHN, 3072, 2048, GHf, nullptr);
      gru_gate<<<2048, 256, 0, stream>>>(GIf + (size_t)lt * BATCHN * 3072, GHf, bhh, Hf, HBF[cur ^ 1]);
      cur ^= 1;
    }
  }

  write_out_kernel<<<2048, 256, 0, stream>>>(Hf, (float*)d_out);
}